// Round 3
// baseline (685.501 us; speedup 1.0000x reference)
//
#include <hip/hip_runtime.h>
#include <hip/hip_fp16.h>

// DynamicRouting (capsule routing), MI355X / gfx950.
// votes: [B=128, I=2048, O=32, P=4] fp32 (128 MiB). activations_in unused.
// b_ij^(t)[b,i,o] = sum_{tau<t} dot(votes[b,i,o,:], v^tau[b,o,:]) -> b_ij never materialized.
//
// R8 changes vs R7 (649 us; fused kernel 522 us):
//  R6/R7 both tried REGISTER-resident votes; both times the backend targeted
//  8 waves/EU (VGPR_Count=64) and spilled all vote state to scratch
//  (WRITE_SIZE 225-231 MB, 2% VALUBusy). Source-level occupancy pins didn't take.
//  Fix: LDS-resident votes. 37.4 KiB LDS/block bounds occupancy to 4 blocks/CU
//  (4 waves/EU), which HANDS the allocator a 128-VGPR budget via the normal
//  occupancy calculation -- and per-thread live state is now only ~40 VGPRs
//  (votes live in LDS, not registers), so nothing can spill.
//   - CHUNKS=16 blocks per b, 128 i/block -> fp16 vote tile 128x32x8B = 32 KiB LDS
//   - grid = 1024 PERSISTENT blocks (256 CU x 4, all co-resident by LDS bound),
//     2 rounds: block handles b0 and b0+64. Barrier couples only the 16 blocks
//     of one b (per-b counter, release atomicAdd + acquire spin -- proven R6/R7).
//   - t1/t2 read votes from LDS (69 TB/s) instead of L3/HBM re-reads.
//  Numerics = R5/R6/R7: t=0 sum fp32 from original votes, t=1/2 fp16 (absmax 0.0039).

#define BATCH 128
#define IC 2048
#define OC 32
#define POSE 4
#define REPS 1e-7f
#define CHUNKS 16
#define CHUNK_I (IC / CHUNKS)             // 128 input capsules per block
#define BLOCK_T 256
#define GROUPS (BLOCK_T / 32)             // 8 o-groups of 32 lanes
#define ILP 4
#define IPT (CHUNK_I / GROUPS)            // 16 i's per thread
#define STEPS (IPT / ILP)                 // 4 accum steps of 4 quads
#define ROUNDS 2                          // 1024 blocks x 2 rounds = 2048 chunk-jobs

// partials layout: [t][b][chunk][o] float4
#define PART_IDX(t, b, c, o) ((((size_t)(t) * BATCH + (b)) * CHUNKS + (c)) * OC + (o))

// ---- fp16 pack/unpack (2x __half2 bit-cast through uint2) ----
__device__ __forceinline__ uint2 packh(const float4 v) {
    union { __half2 h; unsigned u; } a, b;
    a.h = __float22half2_rn(make_float2(v.x, v.y));
    b.h = __float22half2_rn(make_float2(v.z, v.w));
    return make_uint2(a.u, b.u);
}
__device__ __forceinline__ float4 unpackh(const uint2 q) {
    union { unsigned u; __half2 h; } a, b;
    a.u = q.x; b.u = q.y;
    const float2 f0 = __half22float2(a.h);
    const float2 f1 = __half22float2(b.h);
    return make_float4(f0.x, f0.y, f1.x, f1.y);
}

__device__ __forceinline__ float dot4(const float4 a, const float4 b) {
    return a.x*b.x + a.y*b.y + a.z*b.z + a.w*b.w;
}

// squash: v = (n2/(1+n2)) * s / sqrt(n2),  n2 = |s|^2 + eps
__device__ __forceinline__ float4 squash4(const float4 s) {
    const float n2 = s.x*s.x + s.y*s.y + s.z*s.z + s.w*s.w + REPS;
    const float f = n2 / (1.f + n2) * rsqrtf(n2);
    return make_float4(f*s.x, f*s.y, f*s.z, f*s.w);
}

// sum the 16 chunk partials for (b,o) of iteration t, apply scale, squash
__device__ __forceinline__ float4 reduce_squash(
    const float4* __restrict__ partials, int t, int b, int o, float scale)
{
    float4 acc = make_float4(0.f, 0.f, 0.f, 0.f);
    #pragma unroll
    for (int c = 0; c < CHUNKS; ++c) {
        const float4 p = partials[PART_IDX(t, b, c, o)];
        acc.x += p.x; acc.y += p.y; acc.z += p.z; acc.w += p.w;
    }
    acc.x *= scale; acc.y *= scale; acc.z *= scale; acc.w *= scale;
    return squash4(acc);
}

// block-reduce 8 group partials per o, write one chunk partial (no atomics)
__device__ __forceinline__ void block_reduce_store(
    float4 s_acc, float4* lds_s, float4* __restrict__ partials,
    int t, int b, int chunk, int g, int o)
{
    lds_s[g * 32 + o] = s_acc;
    __syncthreads();
    if (threadIdx.x < 32) {
        float4 tot = lds_s[o];
        #pragma unroll
        for (int gg = 1; gg < GROUPS; ++gg) {
            const float4 x = lds_s[gg * 32 + o];
            tot.x += x.x; tot.y += x.y; tot.z += x.z; tot.w += x.w;
        }
        partials[PART_IDX(t, b, chunk, o)] = tot;   // 512 B coalesced
    }
}

// per-b barrier: monotonic counter, CHUNKS arrivals per phase (proven in R6/R7).
// __syncthreads drains this block's partial stores before the release add;
// __threadfence orders/publishes across XCDs.
__device__ __forceinline__ void bar_arrive(unsigned int* cnt) {
    __syncthreads();
    if (threadIdx.x == 0) {
        __threadfence();
        __hip_atomic_fetch_add(cnt, 1u, __ATOMIC_RELEASE, __HIP_MEMORY_SCOPE_AGENT);
    }
}
__device__ __forceinline__ void bar_wait(unsigned int* cnt, unsigned int target) {
    if (threadIdx.x == 0) {
        while (__hip_atomic_load(cnt, __ATOMIC_ACQUIRE, __HIP_MEMORY_SCOPE_AGENT) < target)
            __builtin_amdgcn_s_sleep(2);
        __threadfence();   // invalidate stale lines before the block reads partials
    }
    __syncthreads();
}

// softmax over o (32 lanes) + weighted accumulate for 4 LDS-resident quads
__device__ __forceinline__ void accum4(const uint2 q0, const uint2 q1,
                                       const uint2 q2, const uint2 q3,
                                       const float4 vh, float4& s_acc)
{
    const float4 v0 = unpackh(q0);
    const float4 v1 = unpackh(q1);
    const float4 v2 = unpackh(q2);
    const float4 v3 = unpackh(q3);

    const float l0 = dot4(v0, vh);
    const float l1 = dot4(v1, vh);
    const float l2 = dot4(v2, vh);
    const float l3 = dot4(v3, vh);
    // no max-subtraction: |logit| <~ 16 worst case (|vh01|<2) -> fp32 exp safe
    float e0 = __expf(l0), e1 = __expf(l1), e2 = __expf(l2), e3 = __expf(l3);
    float t0 = e0, t1 = e1, t2 = e2, t3 = e3;
    // butterfly sums over the 32-lane o-group; 4 independent chains interleave
    #pragma unroll
    for (int d = 16; d >= 1; d >>= 1) {
        t0 += __shfl_xor(t0, d);
        t1 += __shfl_xor(t1, d);
        t2 += __shfl_xor(t2, d);
        t3 += __shfl_xor(t3, d);
    }
    const float c0 = e0 * __builtin_amdgcn_rcpf(t0);
    const float c1 = e1 * __builtin_amdgcn_rcpf(t1);
    const float c2 = e2 * __builtin_amdgcn_rcpf(t2);
    const float c3 = e3 * __builtin_amdgcn_rcpf(t3);

    s_acc.x += c0*v0.x + c1*v1.x + c2*v2.x + c3*v3.x;
    s_acc.y += c0*v0.y + c1*v1.y + c2*v2.y + c3*v3.y;
    s_acc.z += c0*v0.z + c1*v1.z + c2*v2.z + c3*v3.z;
    s_acc.w += c0*v0.w + c1*v1.w + c2*v2.w + c3*v3.w;
}

__global__ void routing_init(unsigned int* __restrict__ counters) {
    if (threadIdx.x < BATCH) counters[threadIdx.x * 32] = 0;  // one 128B line per b
}

__global__ __launch_bounds__(BLOCK_T)
void routing_fused(
    const float4* __restrict__ votes,
    float* __restrict__ out,             // poses [B,O,P] then acts [B,O,1]
    unsigned int* __restrict__ counters,
    float4* __restrict__ partials)
{
    const int b0    = blockIdx.x >> 4;          // 64 b-groups per round
    const int chunk = blockIdx.x & (CHUNKS - 1);
    const int o     = threadIdx.x & 31;
    const int g     = threadIdx.x >> 5;

    // 32 KiB fp16 vote tile + reduce buffers = 37.4 KiB -> 4 blocks/CU exactly
    __shared__ uint2  votes_s[CHUNK_I * OC];
    __shared__ float4 lds_s[GROUPS * 32];
    __shared__ float4 vh_s[32];

    const int i0 = chunk * CHUNK_I;

    for (int round = 0; round < ROUNDS; ++round) {
        const int b = b0 + 64 * round;
        unsigned int* cnt = counters + (size_t)b * 32;
        const float4* vb = votes + (size_t)b * IC * OC;

        // ---- t=0: stream fp32 votes once, fp16 -> LDS, mean-reduce in fp32 ----
        float4 s0 = make_float4(0.f, 0.f, 0.f, 0.f);
        #pragma unroll
        for (int s = 0; s < IPT; ++s) {
            const int il = s * GROUPS + g;                    // 0..127
            const float4 v = vb[(size_t)(i0 + il) * OC + o];  // 1 KiB contiguous/wave
            s0.x += v.x; s0.y += v.y; s0.z += v.z; s0.w += v.w;
            votes_s[il * OC + o] = packh(v);                  // 8B/lane, 2-way bank (free)
        }
        // softmax(0) == 1/32 uniform; 1/32 applied at the reduce
        block_reduce_store(s0, lds_s, partials, 0, b, chunk, g, o);
        bar_arrive(cnt);
        bar_wait(cnt, 1 * CHUNKS);

        // ---- t=1 ----
        if (threadIdx.x < 32)
            vh_s[o] = reduce_squash(partials, 0, b, o, 1.f / 32.f);
        __syncthreads();
        const float4 vh0 = vh_s[o];             // keep v^0 for t=2 (no re-reduce)

        float4 s1 = make_float4(0.f, 0.f, 0.f, 0.f);
        #pragma unroll
        for (int s = 0; s < STEPS; ++s) {
            const int base = (s * ILP) * GROUPS + g;
            const uint2 q0 = votes_s[(base + 0 * GROUPS) * OC + o];
            const uint2 q1 = votes_s[(base + 1 * GROUPS) * OC + o];
            const uint2 q2 = votes_s[(base + 2 * GROUPS) * OC + o];
            const uint2 q3 = votes_s[(base + 3 * GROUPS) * OC + o];
            accum4(q0, q1, q2, q3, vh0, s1);
        }
        block_reduce_store(s1, lds_s, partials, 1, b, chunk, g, o);
        bar_arrive(cnt);
        bar_wait(cnt, 2 * CHUNKS);

        // ---- t=2: logit = dot(v, vh0) + dot(v, vh1) == dot(v, vh0+vh1) ----
        if (threadIdx.x < 32)
            vh_s[o] = reduce_squash(partials, 1, b, o, 1.f);
        __syncthreads();
        float4 vh01 = vh_s[o];
        vh01.x += vh0.x; vh01.y += vh0.y; vh01.z += vh0.z; vh01.w += vh0.w;

        float4 s2 = make_float4(0.f, 0.f, 0.f, 0.f);
        #pragma unroll
        for (int s = 0; s < STEPS; ++s) {
            const int base = (s * ILP) * GROUPS + g;
            const uint2 q0 = votes_s[(base + 0 * GROUPS) * OC + o];
            const uint2 q1 = votes_s[(base + 1 * GROUPS) * OC + o];
            const uint2 q2 = votes_s[(base + 2 * GROUPS) * OC + o];
            const uint2 q3 = votes_s[(base + 3 * GROUPS) * OC + o];
            accum4(q0, q1, q2, q3, vh01, s2);
        }
        block_reduce_store(s2, lds_s, partials, 2, b, chunk, g, o);
        bar_arrive(cnt);

        // ---- finalize: chunk-0 block of each b reduces + writes its 32 outputs ----
        if (chunk == 0) {
            bar_wait(cnt, 3 * CHUNKS);
            if (threadIdx.x < 32) {
                const float4 v = reduce_squash(partials, 2, b, o, 1.f);
                ((float4*)out)[b * OC + o] = v;                          // poses_out
                const float a = sqrtf(v.x*v.x + v.y*v.y + v.z*v.z + v.w*v.w + REPS);
                out[BATCH * OC * POSE + b * OC + o] = a;                 // activations
            }
        }
        // votes_s overwrite in next round is safe: last reads happen before the
        // __syncthreads inside this round's final bar_arrive/bar_wait.
    }
}

extern "C" void kernel_launch(void* const* d_in, const int* in_sizes, int n_in,
                              void* d_out, int out_size, void* d_ws, size_t ws_size,
                              hipStream_t stream) {
    const float4* votes = (const float4*)d_in[0];
    // d_in[1] (activations_in) unused by the reference.

    // ws layout: counters (16 KiB, one 128B line per b) | partials (3 MiB)
    unsigned int* counters = (unsigned int*)d_ws;
    float4* partials = (float4*)((char*)d_ws + 16 * 1024);

    routing_init<<<1, 128, 0, stream>>>(counters);
    routing_fused<<<(BATCH / ROUNDS) * CHUNKS, BLOCK_T, 0, stream>>>(
        votes, (float*)d_out, counters, partials);
}

// Round 4
// 234.549 us; speedup vs baseline: 2.9226x; 2.9226x over previous
//
#include <hip/hip_runtime.h>

// DynamicRouting (capsule routing), MI355X / gfx950.
// votes: [B=128, I=2048, O=32, P=4] fp32 (128 MiB). activations_in unused.
// b_ij^(t)[b,i,o] = sum_{tau<t} dot(votes[b,i,o,:], v^tau[b,o,:]) -> b_ij never materialized.
//
// R9 changes vs R8 (686 us; fused kernel 565 us):
//  POST-MORTEM: R6=516, R7=522, R8=565 us across three different storage schemes
//  (reg-spill, reg-spill, clean LDS) -- the constant ~520+ us is NOT storage, it is
//  the cross-block counter barrier (agent-scope acquire spins + __threadfence =
//  cross-XCD L2 writeback/invalidate, x1024 blocks x phases). Barrier design dropped.
//  New structure -- NO inter-block synchronization:
//   - kernel A (2048 blk x 256): t=0 streaming sum of fp32 votes -> chunk partials.
//     Pure HBM stream, ~22 us.
//   - kernel B (128 blk x 1024, ONE b PER BLOCK): the block owns all I=2048 of its b,
//     so v^0 -> t1 -> v^1 -> t2 -> out needs only __syncthreads. Votes re-read twice
//     from L3 (128 MiB just streamed by A, fully L3-resident; 268 MB at L3 rate).
//   - no fp16 copy, no counters, no fences; full fp32 (absmax ~1e-5, was 3.9e-3).
//   - no per-thread state crosses a sync point -> the R6/R7 spill mode is
//     structurally impossible (quads are loop-local).

#define BATCH 128
#define IC 2048
#define OC 32
#define POSE 4
#define REPS 1e-7f

// ---- kernel A geometry ----
#define A_CHUNKS 16
#define A_CHUNK_I (IC / A_CHUNKS)        // 128 input capsules per block
#define A_BLOCK 256
#define A_GROUPS (A_BLOCK / 32)          // 8 i-groups per block
#define A_IPT (A_CHUNK_I / A_GROUPS)     // 16 i's per thread

// ---- kernel B geometry ----
#define B_BLOCK 1024
#define B_GROUPS (B_BLOCK / 32)          // 32 i-groups
#define B_IPT (IC / B_GROUPS)            // 64 i's per thread
#define B_ILP 4
#define B_STEPS (B_IPT / B_ILP)          // 16 steps of 4 quads

// partials layout: [b][chunk][o] float4 (t=0 only)
#define APART(b, c, o) (((size_t)(b) * A_CHUNKS + (c)) * OC + (o))

__device__ __forceinline__ float dot4(const float4 a, const float4 b) {
    return a.x*b.x + a.y*b.y + a.z*b.z + a.w*b.w;
}

// squash: v = (n2/(1+n2)) * s / sqrt(n2),  n2 = |s|^2 + eps
__device__ __forceinline__ float4 squash4(const float4 s) {
    const float n2 = s.x*s.x + s.y*s.y + s.z*s.z + s.w*s.w + REPS;
    const float f = n2 / (1.f + n2) * rsqrtf(n2);
    return make_float4(f*s.x, f*s.y, f*s.z, f*s.w);
}

// softmax over o (32 lanes) + weighted accumulate for 4 fp32 quads.
// __shfl_xor with masks 16..1 stays within each 32-lane half of the wave64,
// i.e. reduces exactly over the o-group (lane = o + 32*(g&1)).
__device__ __forceinline__ void accum4f(const float4 v0, const float4 v1,
                                        const float4 v2, const float4 v3,
                                        const float4 vh, float4& s_acc)
{
    const float l0 = dot4(v0, vh);
    const float l1 = dot4(v1, vh);
    const float l2 = dot4(v2, vh);
    const float l3 = dot4(v3, vh);
    // no max-subtraction: |logit| <~ 16 worst case (|vh01|<2) -> fp32 exp safe
    float e0 = __expf(l0), e1 = __expf(l1), e2 = __expf(l2), e3 = __expf(l3);
    float t0 = e0, t1 = e1, t2 = e2, t3 = e3;
    #pragma unroll
    for (int d = 16; d >= 1; d >>= 1) {
        t0 += __shfl_xor(t0, d);
        t1 += __shfl_xor(t1, d);
        t2 += __shfl_xor(t2, d);
        t3 += __shfl_xor(t3, d);
    }
    const float c0 = e0 * __builtin_amdgcn_rcpf(t0);
    const float c1 = e1 * __builtin_amdgcn_rcpf(t1);
    const float c2 = e2 * __builtin_amdgcn_rcpf(t2);
    const float c3 = e3 * __builtin_amdgcn_rcpf(t3);

    s_acc.x += c0*v0.x + c1*v1.x + c2*v2.x + c3*v3.x;
    s_acc.y += c0*v0.y + c1*v1.y + c2*v2.y + c3*v3.y;
    s_acc.z += c0*v0.z + c1*v1.z + c2*v2.z + c3*v3.z;
    s_acc.w += c0*v0.w + c1*v1.w + c2*v2.w + c3*v3.w;
}

// ---- kernel A: t=0 partial sums (softmax(0) = 1/32 uniform; scale applied in B) ----
__global__ __launch_bounds__(A_BLOCK) void routing_t0(
    const float4* __restrict__ votes,
    float4* __restrict__ partials)
{
    const int b     = blockIdx.x >> 4;          // A_CHUNKS=16
    const int chunk = blockIdx.x & (A_CHUNKS - 1);
    const int o     = threadIdx.x & 31;
    const int g     = threadIdx.x >> 5;

    __shared__ float4 lds_s[A_GROUPS * 32];

    const float4* vb = votes + ((size_t)b * IC + (size_t)chunk * A_CHUNK_I) * OC;

    float4 s0 = make_float4(0.f, 0.f, 0.f, 0.f);
    #pragma unroll
    for (int s = 0; s < A_IPT; ++s) {
        const float4 v = vb[(size_t)(s * A_GROUPS + g) * OC + o];  // 1 KiB/wave
        s0.x += v.x; s0.y += v.y; s0.z += v.z; s0.w += v.w;
    }

    lds_s[g * 32 + o] = s0;
    __syncthreads();
    if (threadIdx.x < 32) {
        float4 tot = lds_s[o];
        #pragma unroll
        for (int gg = 1; gg < A_GROUPS; ++gg) {
            const float4 x = lds_s[gg * 32 + o];
            tot.x += x.x; tot.y += x.y; tot.z += x.z; tot.w += x.w;
        }
        partials[APART(b, chunk, o)] = tot;     // 512 B coalesced
    }
}

// ---- kernel B: one b per block; v0 -> t1 -> v1 -> t2 -> out, __syncthreads only ----
__global__ __launch_bounds__(B_BLOCK) void routing_t12(
    const float4* __restrict__ votes,
    const float4* __restrict__ partials,
    float* __restrict__ out)             // poses [B,O,P] then acts [B,O,1]
{
    const int b = blockIdx.x;
    const int o = threadIdx.x & 31;
    const int g = threadIdx.x >> 5;      // 0..31

    __shared__ float4 lds_s[B_GROUPS * 32];   // 16 KiB reduce buffer
    __shared__ float4 vh_s[32];

    // v^0 = squash((1/32) * sum_i votes) from kernel A's chunk partials
    if (threadIdx.x < 32) {
        float4 acc = make_float4(0.f, 0.f, 0.f, 0.f);
        #pragma unroll
        for (int c = 0; c < A_CHUNKS; ++c) {
            const float4 p = partials[APART(b, c, o)];
            acc.x += p.x; acc.y += p.y; acc.z += p.z; acc.w += p.w;
        }
        const float sc = 1.f / 32.f;
        acc.x *= sc; acc.y *= sc; acc.z *= sc; acc.w *= sc;
        vh_s[o] = squash4(acc);
    }
    __syncthreads();
    const float4 vh0 = vh_s[o];

    const float4* vb = votes + (size_t)b * IC * OC;

    // ---- t=1: pass over votes (L3-resident), logits = dot(v, vh0) ----
    float4 s1 = make_float4(0.f, 0.f, 0.f, 0.f);
    #pragma unroll 2
    for (int st = 0; st < B_STEPS; ++st) {
        const int base = st * (B_ILP * B_GROUPS) + g;       // i = base + k*32
        const float4 v0 = vb[(size_t)(base + 0 * B_GROUPS) * OC + o];
        const float4 v1 = vb[(size_t)(base + 1 * B_GROUPS) * OC + o];
        const float4 v2 = vb[(size_t)(base + 2 * B_GROUPS) * OC + o];
        const float4 v3 = vb[(size_t)(base + 3 * B_GROUPS) * OC + o];
        accum4f(v0, v1, v2, v3, vh0, s1);
    }
    lds_s[g * 32 + o] = s1;
    __syncthreads();
    if (threadIdx.x < 32) {
        float4 tot = lds_s[o];
        #pragma unroll
        for (int gg = 1; gg < B_GROUPS; ++gg) {
            const float4 x = lds_s[gg * 32 + o];
            tot.x += x.x; tot.y += x.y; tot.z += x.z; tot.w += x.w;
        }
        vh_s[o] = squash4(tot);                 // v^1
    }
    __syncthreads();

    // ---- t=2: logit = dot(v, vh0) + dot(v, vh1) == dot(v, vh0+vh1) ----
    float4 vh01 = vh_s[o];
    vh01.x += vh0.x; vh01.y += vh0.y; vh01.z += vh0.z; vh01.w += vh0.w;
    __syncthreads();                            // protect lds_s reuse

    float4 s2 = make_float4(0.f, 0.f, 0.f, 0.f);
    #pragma unroll 2
    for (int st = 0; st < B_STEPS; ++st) {
        const int base = st * (B_ILP * B_GROUPS) + g;
        const float4 v0 = vb[(size_t)(base + 0 * B_GROUPS) * OC + o];
        const float4 v1 = vb[(size_t)(base + 1 * B_GROUPS) * OC + o];
        const float4 v2 = vb[(size_t)(base + 2 * B_GROUPS) * OC + o];
        const float4 v3 = vb[(size_t)(base + 3 * B_GROUPS) * OC + o];
        accum4f(v0, v1, v2, v3, vh01, s2);
    }
    lds_s[g * 32 + o] = s2;
    __syncthreads();
    if (threadIdx.x < 32) {
        float4 tot = lds_s[o];
        #pragma unroll
        for (int gg = 1; gg < B_GROUPS; ++gg) {
            const float4 x = lds_s[gg * 32 + o];
            tot.x += x.x; tot.y += x.y; tot.z += x.z; tot.w += x.w;
        }
        const float4 v = squash4(tot);          // v^2 = poses_out
        ((float4*)out)[b * OC + o] = v;
        const float a = sqrtf(v.x*v.x + v.y*v.y + v.z*v.z + v.w*v.w + REPS);
        out[BATCH * OC * POSE + b * OC + o] = a;   // activations (keepdims norm)
    }
}

extern "C" void kernel_launch(void* const* d_in, const int* in_sizes, int n_in,
                              void* d_out, int out_size, void* d_ws, size_t ws_size,
                              hipStream_t stream) {
    const float4* votes = (const float4*)d_in[0];
    // d_in[1] (activations_in) unused by the reference.

    // ws layout: t=0 chunk partials only (1 MiB)
    float4* partials = (float4*)d_ws;

    routing_t0<<<BATCH * A_CHUNKS, A_BLOCK, 0, stream>>>(votes, partials);
    routing_t12<<<BATCH, B_BLOCK, 0, stream>>>(votes, partials, (float*)d_out);
}